// Round 2
// baseline (473.148 us; speedup 1.0000x reference)
//
#include <hip/hip_runtime.h>
#include <hip/hip_bf16.h>
#include <cstdint>
#include <cstddef>

#define BB 16
#define NN 128
#define MM 1024
#define DN 512
#define DE 256
#define WN 128
#define WE 128
#define PP 512
#define HIDW 256
#define CIW 512

typedef __attribute__((ext_vector_type(8))) short s16x8;
typedef __attribute__((ext_vector_type(4))) float f32x4;

__device__ __forceinline__ float bf2f(unsigned short u) {
    unsigned int x = ((unsigned int)u) << 16;
    union { unsigned int i; float f; } c; c.i = x; return c.f;
}
__device__ __forceinline__ short f2b(float f) {
    __hip_bfloat16 h = __float2bfloat16(f);
    return *reinterpret_cast<short*>(&h);
}

// async global->LDS, 16 bytes per lane. LDS dest must be
// wave-uniform base + lane*16 (linear), global src is per-lane.
__device__ __forceinline__ void gl_lds16(const ushort* g, ushort* l) {
    __builtin_amdgcn_global_load_lds(
        (const __attribute__((address_space(1))) unsigned int*)g,
        (__attribute__((address_space(3))) unsigned int*)l,
        16, 0, 0);
}

// ---------------------------------------------------------------- K0:
// prep all bf16 transposed weights:
//   W1t [768][512], WncT [256][512] (=[Wn|Wn2]^T), WeT [128][256],
//   We2T [128][256], b1cat[768]
__global__ __launch_bounds__(256) void k0_prep(
    const float* __restrict__ lrW1, const float* __restrict__ scrW1,
    const float* __restrict__ mrW1,
    const float* __restrict__ lrb1, const float* __restrict__ scrb1,
    const float* __restrict__ mrb1,
    const float* __restrict__ Wn, const float* __restrict__ Wn2,
    const float* __restrict__ We, const float* __restrict__ We2,
    __hip_bfloat16* __restrict__ W1t, __hip_bfloat16* __restrict__ WncT,
    __hip_bfloat16* __restrict__ WeT, __hip_bfloat16* __restrict__ We2T,
    float* __restrict__ b1cat)
{
    int blk = blockIdx.x;
    int t = threadIdx.x;
    if (blk < 768) {
        int h = blk >> 8, n = blk & 255;
        const float* W = (h == 0) ? lrW1 : (h == 1) ? scrW1 : mrW1;
        W1t[(size_t)blk * 512 + t]       = __float2bfloat16(W[t * 256 + n]);
        W1t[(size_t)blk * 512 + t + 256] = __float2bfloat16(W[(t + 256) * 256 + n]);
    } else if (blk == 768) {
        b1cat[t]       = lrb1[t];
        b1cat[256 + t] = scrb1[t];
        b1cat[512 + t] = mrb1[t];
    } else if (blk < 897) {            // WeT rows 0..127
        int n = blk - 769;
        WeT[(size_t)n * 256 + t] = __float2bfloat16(We[t * 128 + n]);
    } else if (blk < 1153) {           // WncT rows 0..255
        int n = blk - 897;
        const float* W = (n < 128) ? Wn : Wn2;
        int c = n & 127;
        WncT[(size_t)n * 512 + t]       = __float2bfloat16(W[t * 128 + c]);
        WncT[(size_t)n * 512 + t + 256] = __float2bfloat16(W[(t + 256) * 128 + c]);
    } else {                           // We2T rows 0..127
        int n = blk - 1153;
        We2T[(size_t)n * 256 + t] = __float2bfloat16(We2[t * 128 + n]);
    }
}

// ---------------------------------------------------------------- FPROJ:
// One MFMA GEMM kernel, 3 routes (gather fused into A-staging):
//  route0 (blk   0..31 ): [Xmask]@[Wn|Wn2]  M=2048 N=256 K=512 -> Y,Xp f32
//  route1 (blk  32..159): [Eg*emask]@We     M=16384 N=128 K=256 -> G1 f32
//  route2 (blk 160..223): relu(ef_pair@We2) M=8192 N=128 K=256 -> ci[:,384:]
__global__ __launch_bounds__(256) void fproj(
    const float* __restrict__ nf, const float* __restrict__ ef,
    const int* __restrict__ eidx, const int* __restrict__ opair,
    const int* __restrict__ nobj, const int* __restrict__ nedg,
    const ushort* __restrict__ WncT, const ushort* __restrict__ WeT,
    const ushort* __restrict__ We2T,
    float* __restrict__ Y, float* __restrict__ Xp,
    float* __restrict__ G1, __hip_bfloat16* __restrict__ ci)
{
    __shared__ ushort As[128 * 32];
    __shared__ ushort Bs[128 * 32];
    __shared__ unsigned rowoff[128];
    __shared__ float    rowval[128];

    int blk = blockIdx.x;
    int route, mb, nb, K;
    const ushort* Bt;
    if (blk < 32)       { route = 0; mb = blk >> 1;  nb = blk & 1; K = 512; Bt = WncT; }
    else if (blk < 160) { route = 1; mb = blk - 32;  nb = 0;       K = 256; Bt = WeT;  }
    else                { route = 2; mb = blk - 160; nb = 0;       K = 256; Bt = We2T; }
    int row0 = mb * 128, col0 = nb * 128;
    int t = threadIdx.x;

    if (t < 128) {
        int r = row0 + t;
        unsigned off; float valid = 1.f;
        if (route == 0) {
            int b = r >> 7, i = r & 127;
            off = (unsigned)r * DN;
            valid = (i < nobj[b]) ? 1.f : 0.f;
        } else if (route == 1) {
            int b = r >> 10, m = r & 1023;
            int src = eidx[b * 2 * MM + m];
            int dst = eidx[b * 2 * MM + MM + m];
            off = (unsigned)((b * NN + src) * NN + dst) * DE;
            valid = (m < nedg[b]) ? 1.f : 0.f;
        } else {
            int r2 = r;
            int b = r2 >> 9, p = r2 & 511;
            int i0 = opair[(b * PP + p) * 2];
            int i1 = opair[(b * PP + p) * 2 + 1];
            off = (unsigned)((b * NN + i0) * NN + i1) * DE;
        }
        rowoff[t] = off; rowval[t] = valid;
    }

    const float* Asrc = (route == 0) ? nf : ef;
    int lane = t & 63;
    int w    = t >> 6;
    int wr   = w >> 1, wc = w & 1;
    int arow = w * 32 + (lane >> 2);
    int ak   = (lane & 3) * 8;
    int qk   = (lane >> 4) * 8;
    int fr   = lane & 15;
    int sr   = t >> 2;          // staging row for gl_lds (0..63)
    int sk   = (t & 3) * 8;     // staging k-offset
    f32x4 acc[4][4];
    #pragma unroll
    for (int i = 0; i < 4; ++i)
        #pragma unroll
        for (int j = 0; j < 4; ++j) acc[i][j] = (f32x4){0.f, 0.f, 0.f, 0.f};

    for (int k0 = 0; k0 < K; k0 += 32) {
        __syncthreads();
        // B tile: async global->LDS, 2 x 16B per thread, linear dest
        gl_lds16(&Bt[(size_t)(col0 + sr) * K + k0 + sk],      &Bs[t * 8]);
        gl_lds16(&Bt[(size_t)(col0 + sr + 64) * K + k0 + sk], &Bs[t * 8 + 2048]);
        // A tile: gather rows + mask + f32->bf16 (register staged)
        {
            unsigned o0 = rowoff[arow] + k0 + ak;
            unsigned o1 = rowoff[arow + 16] + k0 + ak;
            float m0 = rowval[arow], m1 = rowval[arow + 16];
            float4 a0 = *(const float4*)&Asrc[o0];
            float4 a1 = *(const float4*)&Asrc[o0 + 4];
            float4 b0 = *(const float4*)&Asrc[o1];
            float4 b1 = *(const float4*)&Asrc[o1 + 4];
            s16x8 pa, pb;
            pa[0]=f2b(a0.x*m0); pa[1]=f2b(a0.y*m0); pa[2]=f2b(a0.z*m0); pa[3]=f2b(a0.w*m0);
            pa[4]=f2b(a1.x*m0); pa[5]=f2b(a1.y*m0); pa[6]=f2b(a1.z*m0); pa[7]=f2b(a1.w*m0);
            pb[0]=f2b(b0.x*m1); pb[1]=f2b(b0.y*m1); pb[2]=f2b(b0.z*m1); pb[3]=f2b(b0.w*m1);
            pb[4]=f2b(b1.x*m1); pb[5]=f2b(b1.y*m1); pb[6]=f2b(b1.z*m1); pb[7]=f2b(b1.w*m1);
            *(s16x8*)&As[arow * 32 + ak]        = pa;
            *(s16x8*)&As[(arow + 16) * 32 + ak] = pb;
        }
        __syncthreads();   // drains vmcnt (gl_lds) + lgkmcnt (ds_write)
        s16x8 af[4], bfv[4];
        #pragma unroll
        for (int mi = 0; mi < 4; ++mi)
            af[mi] = *(const s16x8*)&As[(wr * 64 + mi * 16 + fr) * 32 + qk];
        #pragma unroll
        for (int ni = 0; ni < 4; ++ni)
            bfv[ni] = *(const s16x8*)&Bs[(wc * 64 + ni * 16 + fr) * 32 + qk];
        #pragma unroll
        for (int mi = 0; mi < 4; ++mi)
            #pragma unroll
            for (int ni = 0; ni < 4; ++ni)
                acc[mi][ni] = __builtin_amdgcn_mfma_f32_16x16x32_bf16(
                    af[mi], bfv[ni], acc[mi][ni], 0, 0, 0);
    }
    int crow = (lane >> 4) * 4;
    #pragma unroll
    for (int mi = 0; mi < 4; ++mi) {
        #pragma unroll
        for (int ni = 0; ni < 4; ++ni) {
            int gc = col0 + wc * 64 + ni * 16 + fr;
            int gr = row0 + wr * 64 + mi * 16 + crow;
            #pragma unroll
            for (int rg = 0; rg < 4; ++rg) {
                float v = acc[mi][ni][rg];
                int r = gr + rg;
                if (route == 0) {
                    if (gc < 128) Y [(size_t)r * WN + gc]       = v;
                    else          Xp[(size_t)r * WN + gc - 128] = v;
                } else if (route == 1) {
                    G1[(size_t)r * WE + gc] = v;
                } else {
                    ci[(size_t)r * CIW + 384 + gc] = __float2bfloat16(fmaxf(v, 0.f));
                }
            }
        }
    }
}

// ---------------------------------------------------------------- K2:
// h = relu(A @ Y); writes node_emb[...,:128]; zeroes agg half.
__global__ __launch_bounds__(256) void k2_gcn_node(
    const float* __restrict__ adj, const int* __restrict__ num_obj,
    const float* __restrict__ Y, float* __restrict__ node_emb)
{
    __shared__ float As[16 * 129];
    int b  = blockIdx.x >> 4;
    int i0 = ((blockIdx.x >> 1) & 7) * 16;
    int ch = blockIdx.x & 1;
    int s  = num_obj[b];
    int t  = threadIdx.x;
    if (t < 128) {
        for (int rr = 0; rr < 16; ++rr) {
            int i = i0 + rr;
            float v = 0.f;
            if (i < s) {
                v = adj[(size_t)(b * NN + i) * NN + t] * ((t < s) ? 1.f : 0.f);
                if (t == i) v += 1.f;
            }
            As[rr * 129 + t] = v;
        }
    }
    __syncthreads();
    int c  = ch * 64 + (t & 63);
    int rb = (t >> 6) * 4;
    float acc[4] = {0.f,0.f,0.f,0.f};
    for (int j = 0; j < NN; ++j) {
        float yv = Y[(b * NN + j) * WN + c];
        #pragma unroll
        for (int r = 0; r < 4; ++r) acc[r] += As[(rb + r) * 129 + j] * yv;
    }
    #pragma unroll
    for (int r = 0; r < 4; ++r) {
        int i = i0 + rb + r;
        node_emb[(b * NN + i) * 256 + c]       = fmaxf(acc[r], 0.f);
        node_emb[(b * NN + i) * 256 + 128 + c] = 0.f;
    }
}

// ---------------------------------------------------------------- K4:
// g[m] = relu(G1[m] + sum_j L[m,j]*G1[j]); scatter-add into agg half.
__global__ __launch_bounds__(128) void k4_line_gcn(
    const float* __restrict__ la, const float* __restrict__ G1,
    const int* __restrict__ eidx, const int* __restrict__ num_edges,
    float* __restrict__ node_emb)
{
    int b = blockIdx.x >> 10;
    int m = blockIdx.x & 1023;
    int se = num_edges[b];
    if (m >= se) return;
    __shared__ int   cnt;
    __shared__ int   idxs[MM];
    __shared__ float vals[MM];
    int t = threadIdx.x;
    if (t == 0) cnt = 0;
    __syncthreads();
    const float* larow = la + ((size_t)b * MM + m) * MM;
    for (int it = 0; it < 8; ++it) {
        int j = it * 128 + t;
        float v = larow[j];
        if (v != 0.f) {
            int pos = atomicAdd(&cnt, 1);
            idxs[pos] = j;
            vals[pos] = v;
        }
    }
    __syncthreads();
    int n = cnt;
    const float* g1b = G1 + (size_t)b * MM * WE;
    float acc = g1b[m * WE + t];
    for (int p = 0; p < n; ++p)
        acc += vals[p] * g1b[idxs[p] * WE + t];
    float g = fmaxf(acc, 0.f);
    int src = eidx[b * 2 * MM + m];
    atomicAdd(&node_emb[(b * NN + src) * 256 + 128 + t], g);
}

// ---------------------------------------------------------------- K5a:
// ci[:,0:384] (bf16) = [emb0+emb1 (256) | relu(Xp0+Xp1) (128)]
__global__ __launch_bounds__(256) void k5a_build_ci(
    const float* __restrict__ node_emb, const float* __restrict__ Xp,
    const int* __restrict__ opairs, const int* __restrict__ num_obj,
    __hip_bfloat16* __restrict__ ci)
{
    __shared__ int   pi0[16], pi1[16];
    __shared__ float nm0[16], nm1[16];
    int b     = blockIdx.x >> 5;
    int pbase = (blockIdx.x & 31) * 16;
    int t     = threadIdx.x;
    int s     = num_obj[b];
    if (t < 16) {
        int p  = pbase + t;
        int i0 = opairs[(b * PP + p) * 2];
        int i1 = opairs[(b * PP + p) * 2 + 1];
        pi0[t] = i0; pi1[t] = i1;
        nm0[t] = (i0 < s) ? 1.f : 0.f;
        nm1[t] = (i1 < s) ? 1.f : 0.f;
    }
    __syncthreads();
    for (int pp = 0; pp < 16; ++pp) {
        int i0 = pi0[pp], i1 = pi1[pp];
        int p  = pbase + pp;
        __hip_bfloat16* cirow = ci + (size_t)(b * PP + p) * CIW;
        float m0f = (t < 128) ? 1.f : nm0[pp];
        float m1f = (t < 128) ? 1.f : nm1[pp];
        float v = node_emb[(b * NN + i0) * 256 + t] * m0f
                + node_emb[(b * NN + i1) * 256 + t] * m1f;
        cirow[t] = __float2bfloat16(v);
        if (t < 128) {
            float pm = Xp[(b * NN + i0) * WN + t] + Xp[(b * NN + i1) * WN + t];
            cirow[256 + t] = __float2bfloat16(fmaxf(pm, 0.f));
        }
    }
}

// ---------------------------------------------------------------- K6:
// hid(bf16) = relu(ci @ W1cat + b1cat), (8192x512)@(512x768), bf16 MFMA.
// A and B both staged via global_load_lds dwordx4 (m97 pattern).
__global__ __launch_bounds__(256) void k6_mlp1_mfma(
    const ushort* __restrict__ A,   // ci  [8192][512] bf16
    const ushort* __restrict__ Bt,  // W1t [768][512] bf16 (N-major)
    const float* __restrict__ b1cat,
    __hip_bfloat16* __restrict__ H) // hid [8192][768] bf16
{
    __shared__ ushort As[128 * 32];
    __shared__ ushort Bs[128 * 32];
    int t    = threadIdx.x;
    int col0 = blockIdx.x * 128;
    int row0 = blockIdx.y * 128;
    int lane = t & 63;
    int w    = t >> 6;
    int wr   = w >> 1, wc = w & 1;
    int qk   = (lane >> 4) * 8;
    int fr   = lane & 15;
    int sr   = t >> 2;          // staging row (0..63)
    int sk   = (t & 3) * 8;     // staging k-offset
    f32x4 acc[4][4];
    #pragma unroll
    for (int i = 0; i < 4; ++i)
        #pragma unroll
        for (int j = 0; j < 4; ++j) acc[i][j] = (f32x4){0.f, 0.f, 0.f, 0.f};

    for (int k0 = 0; k0 < CIW; k0 += 32) {
        __syncthreads();
        gl_lds16(&A [(size_t)(row0 + sr) * CIW + k0 + sk],      &As[t * 8]);
        gl_lds16(&A [(size_t)(row0 + sr + 64) * CIW + k0 + sk], &As[t * 8 + 2048]);
        gl_lds16(&Bt[(size_t)(col0 + sr) * CIW + k0 + sk],      &Bs[t * 8]);
        gl_lds16(&Bt[(size_t)(col0 + sr + 64) * CIW + k0 + sk], &Bs[t * 8 + 2048]);
        __syncthreads();   // drains vmcnt before any wave reads LDS
        s16x8 af[4], bfv[4];
        #pragma unroll
        for (int mi = 0; mi < 4; ++mi)
            af[mi] = *(const s16x8*)&As[(wr * 64 + mi * 16 + fr) * 32 + qk];
        #pragma unroll
        for (int ni = 0; ni < 4; ++ni)
            bfv[ni] = *(const s16x8*)&Bs[(wc * 64 + ni * 16 + fr) * 32 + qk];
        #pragma unroll
        for (int mi = 0; mi < 4; ++mi)
            #pragma unroll
            for (int ni = 0; ni < 4; ++ni)
                acc[mi][ni] = __builtin_amdgcn_mfma_f32_16x16x32_bf16(
                    af[mi], bfv[ni], acc[mi][ni], 0, 0, 0);
    }
    int crow = (lane >> 4) * 4;
    #pragma unroll
    for (int mi = 0; mi < 4; ++mi) {
        #pragma unroll
        for (int ni = 0; ni < 4; ++ni) {
            int gc = col0 + wc * 64 + ni * 16 + fr;
            int gr = row0 + wr * 64 + mi * 16 + crow;
            float bias = b1cat[gc];
            #pragma unroll
            for (int rg = 0; rg < 4; ++rg) {
                float v = fmaxf(acc[mi][ni][rg] + bias, 0.f);
                H[(size_t)(gr + rg) * 768 + gc] = __float2bfloat16(v);
            }
        }
    }
}

// ---------------------------------------------------------------- K7:
// out = hid @ W2 + b2 for all 3 heads. 32 lanes/pair (9+6+17=32 cols).
__global__ __launch_bounds__(256) void k7_mlp2(
    const __hip_bfloat16* __restrict__ H,   // [8192][768]
    const float* __restrict__ lrW2, const float* __restrict__ lrb2,
    const float* __restrict__ scrW2, const float* __restrict__ scrb2,
    const float* __restrict__ mrW2, const float* __restrict__ mrb2,
    float* __restrict__ outp)
{
    __shared__ float w2s[32 * 257];
    int t = threadIdx.x;
    for (int o = 0; o < 32; ++o) {
        float v;
        if (o < 9)       v = lrW2[t * 9 + o];
        else if (o < 15) v = scrW2[t * 6 + (o - 9)];
        else             v = mrW2[t * 17 + (o - 15)];
        w2s[o * 257 + t] = v;
    }
    __syncthreads();
    int p = blockIdx.x * 8 + (t >> 5);
    int o = t & 31;
    int seg = (o < 9) ? 0 : ((o < 15) ? 1 : 2);
    const ushort* hr = (const ushort*)H + (size_t)p * 768 + seg * 256;
    const float* wr = &w2s[o * 257];
    float acc = (o < 9) ? lrb2[o] : ((o < 15) ? scrb2[o - 9] : mrb2[o - 15]);
    for (int k = 0; k < HIDW; k += 8) {
        s16x8 u = *(const s16x8*)&hr[k];
        acc += bf2f((unsigned short)u[0]) * wr[k]
             + bf2f((unsigned short)u[1]) * wr[k + 1]
             + bf2f((unsigned short)u[2]) * wr[k + 2]
             + bf2f((unsigned short)u[3]) * wr[k + 3]
             + bf2f((unsigned short)u[4]) * wr[k + 4]
             + bf2f((unsigned short)u[5]) * wr[k + 5]
             + bf2f((unsigned short)u[6]) * wr[k + 6]
             + bf2f((unsigned short)u[7]) * wr[k + 7];
    }
    if (o < 9)       outp[(size_t)p * 9 + o] = acc;
    else if (o < 15) outp[8192 * 9 + (size_t)p * 6 + (o - 9)] = acc;
    else             outp[8192 * 15 + (size_t)p * 17 + (o - 15)] = acc;
}

// ----------------------------------------------------------------
extern "C" void kernel_launch(void* const* d_in, const int* in_sizes, int n_in,
                              void* d_out, int out_size, void* d_ws, size_t ws_size,
                              hipStream_t stream) {
    const float* nf    = (const float*)d_in[0];
    const float* ef    = (const float*)d_in[1];
    const float* adj   = (const float*)d_in[2];
    const float* la    = (const float*)d_in[3];
    const int*   eidx  = (const int*)d_in[4];
    const int*   opair = (const int*)d_in[5];
    const int*   nobj  = (const int*)d_in[6];
    const int*   nedg  = (const int*)d_in[7];
    const float* Wn    = (const float*)d_in[8];
    const float* We    = (const float*)d_in[9];
    const float* Wn2   = (const float*)d_in[10];
    const float* We2   = (const float*)d_in[11];
    const float* scrW1 = (const float*)d_in[12];
    const float* scrb1 = (const float*)d_in[13];
    const float* scrW2 = (const float*)d_in[14];
    const float* scrb2 = (const float*)d_in[15];
    const float* lrW1  = (const float*)d_in[16];
    const float* lrb1  = (const float*)d_in[17];
    const float* lrW2  = (const float*)d_in[18];
    const float* lrb2  = (const float*)d_in[19];
    const float* mrW1  = (const float*)d_in[20];
    const float* mrb1  = (const float*)d_in[21];
    const float* mrW2  = (const float*)d_in[22];
    const float* mrb2  = (const float*)d_in[23];

    float* ws = (float*)d_ws;
    float* Y        = ws;                    // 262144 f32
    float* Xp       = Y + 262144;            // 262144
    float* node_emb = Xp + 262144;           // 524288
    float* G1       = node_emb + 524288;     // 2097152
    float* base     = G1 + 2097152;
    __hip_bfloat16* ci   = (__hip_bfloat16*)base;            // 8192*512  = 2097152 f32 slots
    __hip_bfloat16* hid  = (__hip_bfloat16*)(base + 2097152);// 8192*768  = 3145728 f32 slots
    __hip_bfloat16* W1t  = (__hip_bfloat16*)(base + 2097152 + 3145728);   // 196608 f32
    __hip_bfloat16* WncT = (__hip_bfloat16*)(base + 2097152 + 3145728 + 196608); // 65536 f32
    __hip_bfloat16* WeT  = (__hip_bfloat16*)(base + 2097152 + 3145728 + 196608 + 65536); // 16384
    __hip_bfloat16* We2T = (__hip_bfloat16*)(base + 2097152 + 3145728 + 196608 + 65536 + 16384);
    float* b1cat = base + 2097152 + 3145728 + 196608 + 65536 + 16384 + 16384;

    k0_prep <<<1281, 256, 0, stream>>>(lrW1, scrW1, mrW1, lrb1, scrb1, mrb1,
                                       Wn, Wn2, We, We2,
                                       W1t, WncT, WeT, We2T, b1cat);
    fproj   <<<224, 256, 0, stream>>>(nf, ef, eidx, opair, nobj, nedg,
                                      (const ushort*)WncT, (const ushort*)WeT,
                                      (const ushort*)We2T, Y, Xp, G1, ci);
    k2_gcn_node <<<BB * 8 * 2, 256, 0, stream>>>(adj, nobj, Y, node_emb);
    k4_line_gcn <<<BB * MM, 128, 0, stream>>>(la, G1, eidx, nedg, node_emb);
    k5a_build_ci<<<BB * (PP / 16), 256, 0, stream>>>(node_emb, Xp, opair, nobj, ci);
    k6_mlp1_mfma<<<dim3(6, 64), 256, 0, stream>>>((const ushort*)ci,
                                                  (const ushort*)W1t, b1cat, hid);
    k7_mlp2     <<<8192 / 8, 256, 0, stream>>>(hid, lrW2, lrb2, scrW2, scrb2,
                                               mrW2, mrb2, (float*)d_out);
}